// Round 1
// baseline (130.165 us; speedup 1.0000x reference)
//
#include <hip/hip_runtime.h>
#include <hip/hip_bf16.h>

#define NROWS 4096
#define DIM   768
#define BM 128
#define BN 128
#define BK 32

typedef __attribute__((ext_vector_type(8))) short short8;
typedef __attribute__((ext_vector_type(4))) float f32x4;

#define GAS(p) ((const __attribute__((address_space(1))) void*)(p))
#define SAS(p) ((__attribute__((address_space(3))) void*)(p))

// fp32 -> bf16 round-to-nearest-even (no NaN in this workload)
__device__ __forceinline__ unsigned short f2bf(float x) {
    unsigned int u = __builtin_bit_cast(unsigned int, x);
    u += 0x7fffu + ((u >> 16) & 1u);
    return (unsigned short)(u >> 16);
}

// ---------------- Kernel 1: L2-normalize rows, cast to bf16 ----------------
// one wave per row; blocks [0,4096) -> feature1, [4096,8192) -> feature2
__global__ __launch_bounds__(64) void k_norm(const float* __restrict__ f1,
                                             const float* __restrict__ f2,
                                             unsigned short* __restrict__ n1,
                                             unsigned short* __restrict__ n2) {
    int b = blockIdx.x;
    const float* src = (b < NROWS) ? f1 : f2;
    unsigned short* dst = (b < NROWS) ? n1 : n2;
    int row = b & (NROWS - 1);
    const float4* srow = (const float4*)(src + (size_t)row * DIM);
    int lane = threadIdx.x;
    float4 v[3];
    float ss = 0.f;
#pragma unroll
    for (int r = 0; r < 3; ++r) {
        v[r] = srow[lane + 64 * r];   // 192 float4 = 768 floats, coalesced
        ss += v[r].x * v[r].x + v[r].y * v[r].y + v[r].z * v[r].z + v[r].w * v[r].w;
    }
#pragma unroll
    for (int off = 32; off; off >>= 1) ss += __shfl_xor(ss, off);
    float inv = 1.0f / fmaxf(sqrtf(ss), 1e-8f);   // matches torch/jax eps semantics
    ushort4* drow = (ushort4*)(dst + (size_t)row * DIM);
#pragma unroll
    for (int r = 0; r < 3; ++r) {
        ushort4 o;
        o.x = f2bf(v[r].x * inv);
        o.y = f2bf(v[r].y * inv);
        o.z = f2bf(v[r].z * inv);
        o.w = f2bf(v[r].w * inv);
        drow[lane + 64 * r] = o;
    }
}

// ---------------- Kernel 2: 128x128-tile bf16 MFMA GEMM + fused exp/row-sum ----------------
// logits[i][j] = 20 * dot(n1[i], n2[j]); accumulate rowsum[i] += sum_j exp(logit),
// record diag[i] = logit_ii. m97 structure: 4 waves, each owns a 64x64 subtile,
// BK=32, single-buffered LDS, global_load_lds width-16 staging.
__global__ __launch_bounds__(256) void k_gemm_lse(const unsigned short* __restrict__ n1,
                                                  const unsigned short* __restrict__ n2,
                                                  float* __restrict__ rowsum,
                                                  float* __restrict__ diag) {
    __shared__ alignas(16) unsigned short At[BM * BK];  // [row][k], 64B row stride
    __shared__ alignas(16) unsigned short Bt[BN * BK];  // [col][k] (n2 row-major = B^T)

    // XCD-aware swizzle (1024 % 8 == 0 -> bijective)
    int wg = blockIdx.x;
    int swz = (wg & 7) * (1024 >> 3) + (wg >> 3);
    int bi = swz >> 5;          // 32 i-tiles
    int bj = swz & 31;          // 32 j-tiles

    int tid = threadIdx.x;
    int w = tid >> 6;
    int lane = tid & 63;
    int l15 = lane & 15;
    int lk = lane >> 4;         // 0..3
    int wr = w >> 1, wc = w & 1;   // 2x2 wave grid, each wave 64x64 output

    const unsigned short* Ag = n1 + (size_t)bi * BM * DIM;
    const unsigned short* Bg = n2 + (size_t)bj * BN * DIM;

    // staging: per 4096B call, thread t fills LDS bytes [t*16, t*16+16)
    // = row (t>>2) of 64-row half-tile, k-chunk (t&3)*8 elems
    int srow = tid >> 2;
    int sck = tid & 3;
    const unsigned short* gA = Ag + (size_t)srow * DIM + sck * 8;
    const unsigned short* gB = Bg + (size_t)srow * DIM + sck * 8;
    char* ldsA0 = (char*)At + w * 1024;
    char* ldsA1 = (char*)At + 4096 + w * 1024;
    char* ldsB0 = (char*)Bt + w * 1024;
    char* ldsB1 = (char*)Bt + 4096 + w * 1024;

    f32x4 acc[4][4] = {};

    for (int k0 = 0; k0 < DIM; k0 += BK) {
        __builtin_amdgcn_global_load_lds(GAS(gA + k0), SAS(ldsA0), 16, 0, 0);
        __builtin_amdgcn_global_load_lds(GAS(gA + 64 * DIM + k0), SAS(ldsA1), 16, 0, 0);
        __builtin_amdgcn_global_load_lds(GAS(gB + k0), SAS(ldsB0), 16, 0, 0);
        __builtin_amdgcn_global_load_lds(GAS(gB + 64 * DIM + k0), SAS(ldsB1), 16, 0, 0);
        __syncthreads();   // drains vmcnt before barrier

        short8 a[4], b[4];
#pragma unroll
        for (int mi = 0; mi < 4; ++mi)
            a[mi] = *(const short8*)((const char*)At +
                     ((wr * 64 + mi * 16 + l15) * BK + lk * 8) * 2);
#pragma unroll
        for (int ni = 0; ni < 4; ++ni)
            b[ni] = *(const short8*)((const char*)Bt +
                     ((wc * 64 + ni * 16 + l15) * BK + lk * 8) * 2);
#pragma unroll
        for (int mi = 0; mi < 4; ++mi)
#pragma unroll
            for (int ni = 0; ni < 4; ++ni)
                acc[mi][ni] = __builtin_amdgcn_mfma_f32_16x16x32_bf16(
                                  a[mi], b[ni], acc[mi][ni], 0, 0, 0);
        __syncthreads();   // protect LDS before next iteration's staging
    }

    // Epilogue. C/D layout (HW-verified): col = lane&15, row = (lane>>4)*4 + reg
    const bool diag_sub = (bi == bj) && (wr == wc);
#pragma unroll
    for (int mi = 0; mi < 4; ++mi) {
        float s[4] = {0.f, 0.f, 0.f, 0.f};
#pragma unroll
        for (int ni = 0; ni < 4; ++ni) {
#pragma unroll
            for (int r = 0; r < 4; ++r) {
                float v = acc[mi][ni][r] * 20.0f;   // 1/TEMP
                s[r] += __expf(v);
                if (diag_sub && (mi == ni) && (lk * 4 + r == l15)) {
                    int gi = bi * BM + wr * 64 + mi * 16 + lk * 4 + r;
                    diag[gi] = v;
                }
            }
        }
        // reduce across the 16 lanes of this lk-group (xor 1,2,4,8 stays in-group)
#pragma unroll
        for (int r = 0; r < 4; ++r) {
#pragma unroll
            for (int off = 1; off < 16; off <<= 1) s[r] += __shfl_xor(s[r], off);
        }
        if (l15 == 0) {
#pragma unroll
            for (int r = 0; r < 4; ++r) {
                int gi = bi * BM + wr * 64 + mi * 16 + lk * 4 + r;
                atomicAdd(rowsum + gi, s[r]);
            }
        }
    }
}

// ---------------- Kernel 3: loss = mean(log(rowsum) - diag) ----------------
__global__ __launch_bounds__(256) void k_final(const float* __restrict__ rowsum,
                                               const float* __restrict__ diag,
                                               float* __restrict__ out) {
    int tid = threadIdx.x;
    float s = 0.f;
    for (int i = tid; i < NROWS; i += 256) s += logf(rowsum[i]) - diag[i];
#pragma unroll
    for (int off = 32; off; off >>= 1) s += __shfl_xor(s, off);
    __shared__ float red[4];
    if ((tid & 63) == 0) red[tid >> 6] = s;
    __syncthreads();
    if (tid == 0) out[0] = (red[0] + red[1] + red[2] + red[3]) * (1.0f / NROWS);
}

extern "C" void kernel_launch(void* const* d_in, const int* in_sizes, int n_in,
                              void* d_out, int out_size, void* d_ws, size_t ws_size,
                              hipStream_t stream) {
    const float* f1 = (const float*)d_in[0];
    const float* f2 = (const float*)d_in[1];
    float* out = (float*)d_out;

    char* ws = (char*)d_ws;                       // layout: n1 | n2 | rowsum | diag
    unsigned short* n1 = (unsigned short*)ws;
    unsigned short* n2 = n1 + (size_t)NROWS * DIM;
    float* rowsum = (float*)(ws + 2 * (size_t)NROWS * DIM * sizeof(unsigned short));
    float* diag = rowsum + NROWS;

    hipMemsetAsync(rowsum, 0, NROWS * sizeof(float), stream);
    k_norm<<<2 * NROWS, 64, 0, stream>>>(f1, f2, n1, n2);
    k_gemm_lse<<<1024, 256, 0, stream>>>(n1, n2, rowsum, diag);
    k_final<<<1, 256, 0, stream>>>(rowsum, diag, out);
}

// Round 2
// 104.093 us; speedup vs baseline: 1.2505x; 1.2505x over previous
//
#include <hip/hip_runtime.h>
#include <hip/hip_bf16.h>

#define NROWS 4096
#define DIM   768
#define NKT   12          // 768 / 64 K-tiles

typedef __attribute__((ext_vector_type(8))) short short8;
typedef __attribute__((ext_vector_type(4))) float f32x4;

#define GAS(p) ((const __attribute__((address_space(1))) void*)(p))
#define SAS(p) ((__attribute__((address_space(3))) void*)(p))

// fp32 -> bf16 round-to-nearest-even
__device__ __forceinline__ unsigned short f2bf(float x) {
    unsigned int u = __builtin_bit_cast(unsigned int, x);
    u += 0x7fffu + ((u >> 16) & 1u);
    return (unsigned short)(u >> 16);
}

// ---------------- Kernel 1: L2-normalize rows -> bf16; also zero rowsum ----------------
// 2048 blocks x 256 threads; wave w of block b handles row b*4+w (f1 rows 0-4095, f2 rows 4096-8191)
__global__ __launch_bounds__(256) void k_norm(const float* __restrict__ f1,
                                              const float* __restrict__ f2,
                                              unsigned short* __restrict__ n1,
                                              unsigned short* __restrict__ n2,
                                              float* __restrict__ rowsum) {
    int b = blockIdx.x;
    int wid = threadIdx.x >> 6, lane = threadIdx.x & 63;
    int rowidx = b * 4 + wid;                     // 0..8191, wave-uniform
    const float* src = (rowidx < NROWS) ? f1 : f2;
    unsigned short* dst = (rowidx < NROWS) ? n1 : n2;
    int row = rowidx & (NROWS - 1);
    const float4* srow = (const float4*)(src + (size_t)row * DIM);
    float4 v[3];
    float ss = 0.f;
#pragma unroll
    for (int r = 0; r < 3; ++r) {
        v[r] = srow[lane + 64 * r];
        ss += v[r].x * v[r].x + v[r].y * v[r].y + v[r].z * v[r].z + v[r].w * v[r].w;
    }
#pragma unroll
    for (int off = 32; off; off >>= 1) ss += __shfl_xor(ss, off);
    float inv = 1.0f / fmaxf(sqrtf(ss), 1e-8f);
    ushort4* drow = (ushort4*)(dst + (size_t)row * DIM);
#pragma unroll
    for (int r = 0; r < 3; ++r) {
        ushort4 o;
        o.x = f2bf(v[r].x * inv);
        o.y = f2bf(v[r].y * inv);
        o.z = f2bf(v[r].z * inv);
        o.w = f2bf(v[r].w * inv);
        drow[lane + 64 * r] = o;
    }
    if (b == 0) {                                  // zero rowsum (4096 floats)
        float4 z = {0.f, 0.f, 0.f, 0.f};
#pragma unroll
        for (int i = 0; i < 4; ++i) ((float4*)rowsum)[threadIdx.x + 256 * i] = z;
    }
}

// ---------------- Kernel 2: 256x256-tile 8-phase bf16 MFMA GEMM + fused exp/row-sum ----------------
// 512 threads = 8 waves (2M x 4N), per-wave output 128x64. BK=64, dbuf LDS 128 KiB.
// LDS region(buf, slot): slot A0=0,A1=1 (row halves), B0=2,B1=3. Each region 128x64 bf16 = 16 KiB.
// T2 swizzle: within a 128 B row, byte_in_row ^= ((row&7)<<4); applied on the global SOURCE of
// global_load_lds (LDS dest linear) and on the ds_read address (rule 21: both sides, same involution).

#define BARRIER __builtin_amdgcn_s_barrier()
#define WAIT_LGKM0 do { asm volatile("s_waitcnt lgkmcnt(0)" ::: "memory"); \
                        __builtin_amdgcn_sched_barrier(0); } while (0)
#define WAIT_VM4   do { asm volatile("s_waitcnt vmcnt(4)" ::: "memory"); \
                        __builtin_amdgcn_sched_barrier(0); } while (0)

__global__ __launch_bounds__(512, 2) void k_gemm_lse(const unsigned short* __restrict__ n1,
                                                     const unsigned short* __restrict__ n2,
                                                     float* __restrict__ rowsum,
                                                     float* __restrict__ diag) {
    __shared__ alignas(16) char ldsbuf[131072];
    char* ldsc = (char*)ldsbuf;

    // XCD-aware bijective swizzle (256 % 8 == 0)
    int wg = blockIdx.x;
    int swz = (wg & 7) * 32 + (wg >> 3);
    int bi = swz >> 4;            // 16 i-tiles
    int bj = swz & 15;            // 16 j-tiles

    int tid = threadIdx.x;
    int wid = tid >> 6;
    int lane = tid & 63;
    int l15 = lane & 15, lk = lane >> 4;
    int wr = wid >> 2, wc = wid & 3;   // 2x4 wave grid

    const unsigned short* abase = n1 + (size_t)bi * 256 * DIM;
    const unsigned short* bbase = n2 + (size_t)bj * 256 * DIM;

    // staging: call c covers rows [c*64, c*64+64) of a 128-row half; thread tid writes LDS
    // linear byte c*8192 + tid*16 = (row = c*64 + tid/8, slot16 = tid%8). Source slot is
    // pre-swizzled: src_k16 = (tid%8) ^ ((tid/8)&7).
    const int stoff = (tid >> 3) * DIM + (((tid & 7) ^ ((tid >> 3) & 7)) * 8);

    // ds_read per-lane offsets: addr = regionbase + rowbase*128 + l15*128 + (k2 ^ ((l&7)<<4))
    const int swzl = (lane & 7) << 4;
    const int lko0 = l15 * 128 + ((lk * 16) ^ swzl);          // kstep 0
    const int lko1 = l15 * 128 + (((64 + lk * 16)) ^ swzl);   // kstep 1

    char* LA[2];  // this wave's A half (wr), per buffer
    char* LB[2];  // this wave's B half (wc>>1) + 64-row sub-strip (wc&1), per buffer
    LA[0] = ldsc + (0 * 4 + wr) * 16384;
    LA[1] = ldsc + (1 * 4 + wr) * 16384;
    LB[0] = ldsc + (0 * 4 + 2 + (wc >> 1)) * 16384 + (wc & 1) * (64 * 128);
    LB[1] = ldsc + (1 * 4 + 2 + (wc >> 1)) * 16384 + (wc & 1) * (64 * 128);

#define STG(b, slot, base, half, kt) do { \
    const unsigned short* _s = (base) + ((half) * 128) * DIM + (kt) * 64 + stoff; \
    char* _d = ldsc + ((b) * 4 + (slot)) * 16384 + wid * 1024; \
    __builtin_amdgcn_global_load_lds(GAS(_s), SAS(_d), 16, 0, 0); \
    __builtin_amdgcn_global_load_lds(GAS(_s + 64 * DIM), SAS(_d + 8192), 16, 0, 0); \
} while (0)

#define LDA_(b, qm) do { _Pragma("unroll") for (int m = 0; m < 4; ++m) { \
    const char* _p = LA[b] + ((qm) * 64 + m * 16) * 128; \
    a[m][0] = *(const short8*)(_p + lko0); \
    a[m][1] = *(const short8*)(_p + lko1); } } while (0)

#define LDB_(b, qn, breg) do { _Pragma("unroll") for (int n = 0; n < 2; ++n) { \
    const char* _p = LB[b] + ((qn) * 2 + n) * 16 * 128; \
    breg[n][0] = *(const short8*)(_p + lko0); \
    breg[n][1] = *(const short8*)(_p + lko1); } } while (0)

#define MM_(qm, qn, breg) do { _Pragma("unroll") for (int m = 0; m < 4; ++m) \
    _Pragma("unroll") for (int n = 0; n < 2; ++n) { \
    f32x4* _c = &acc[(qm) * 4 + m][(qn) * 2 + n]; \
    *_c = __builtin_amdgcn_mfma_f32_16x16x32_bf16(a[m][0], breg[n][0], *_c, 0, 0, 0); \
    *_c = __builtin_amdgcn_mfma_f32_16x16x32_bf16(a[m][1], breg[n][1], *_c, 0, 0, 0); } } while (0)

    short8 a[4][2], b0[2][2], b1[2][2];
    f32x4 acc[8][4] = {};

    // Prologue: tile0 all four halves + B halves of tile1. vmcnt(4) leaves {B0(1),B1(1)} in flight.
    STG(0, 0, abase, 0, 0); STG(0, 1, abase, 1, 0);
    STG(0, 2, bbase, 0, 0); STG(0, 3, bbase, 1, 0);
    STG(1, 2, bbase, 0, 1); STG(1, 3, bbase, 1, 1);
    WAIT_VM4;
    BARRIER;

    for (int t = 0; t < NKT; t += 2) {
        int t1 = t + 1;
        int t2 = (t + 2 < NKT) ? t + 2 : t + 2 - NKT;   // wrap: staged-but-never-read on last iter
        int t3 = (t + 3 < NKT) ? t + 3 : t + 3 - NKT;
        // ---- tile t from buf0 ----
        // ph0
        LDA_(0, 0); LDB_(0, 0, b0);
        STG(1, 0, abase, 0, t1);
        BARRIER; WAIT_LGKM0;
        __builtin_amdgcn_s_setprio(1); MM_(0, 0, b0); __builtin_amdgcn_s_setprio(0);
        BARRIER;
        // ph1
        LDB_(0, 1, b1);
        STG(1, 1, abase, 1, t1);
        BARRIER; WAIT_LGKM0;
        __builtin_amdgcn_s_setprio(1); MM_(0, 1, b1); __builtin_amdgcn_s_setprio(0);
        BARRIER;
        // ph2
        LDA_(0, 1);
        STG(0, 2, bbase, 0, t2);
        BARRIER; WAIT_LGKM0;
        __builtin_amdgcn_s_setprio(1); MM_(1, 1, b1); __builtin_amdgcn_s_setprio(0);
        BARRIER;
        // ph3 (no ds_reads; b0/a kept in regs)
        STG(0, 3, bbase, 1, t2);
        BARRIER;
        __builtin_amdgcn_s_setprio(1); MM_(1, 0, b0); __builtin_amdgcn_s_setprio(0);
        WAIT_VM4;      // tile t+1 fully landed; {B0(t+2),B1(t+2)} stay in flight
        BARRIER;
        // ---- tile t+1 from buf1 ----
        // ph4
        LDA_(1, 0); LDB_(1, 0, b0);
        STG(0, 0, abase, 0, t2);
        BARRIER; WAIT_LGKM0;
        __builtin_amdgcn_s_setprio(1); MM_(0, 0, b0); __builtin_amdgcn_s_setprio(0);
        BARRIER;
        // ph5
        LDB_(1, 1, b1);
        STG(0, 1, abase, 1, t2);
        BARRIER; WAIT_LGKM0;
        __builtin_amdgcn_s_setprio(1); MM_(0, 1, b1); __builtin_amdgcn_s_setprio(0);
        BARRIER;
        // ph6
        LDA_(1, 1);
        STG(1, 2, bbase, 0, t3);
        BARRIER; WAIT_LGKM0;
        __builtin_amdgcn_s_setprio(1); MM_(1, 1, b1); __builtin_amdgcn_s_setprio(0);
        BARRIER;
        // ph7
        STG(1, 3, bbase, 1, t3);
        BARRIER;
        __builtin_amdgcn_s_setprio(1); MM_(1, 0, b0); __builtin_amdgcn_s_setprio(0);
        WAIT_VM4;      // tile t+2 fully landed; {B0(t+3),B1(t+3)} stay in flight
        BARRIER;
    }

    __syncthreads();   // drains remaining vmcnt before epilogue / endpgm

    // Epilogue. C/D layout: col = l15, row = lk*4 + r (per 16x16 frag). acc[mi][ni] covers
    // rows wr*128 + mi*16 + lk*4 + r, cols wc*64 + ni*16 + l15.
    const bool dblk = (bi == bj);
    const int rowb = bi * 256 + wr * 128;
    const int colb = bj * 256 + wc * 64;
#pragma unroll
    for (int mi = 0; mi < 8; ++mi) {
#pragma unroll
        for (int r = 0; r < 4; ++r) {
            float s = 0.f;
            int gi = rowb + mi * 16 + lk * 4 + r;
#pragma unroll
            for (int ni = 0; ni < 4; ++ni) {
                float v = acc[mi][ni][r] * 20.0f;    // 1/TEMP
                s += __expf(v);
                if (dblk) {
                    int gj = colb + ni * 16 + l15;
                    if (gi == gj) diag[gi] = v;
                }
            }
#pragma unroll
            for (int off = 1; off < 16; off <<= 1) s += __shfl_xor(s, off);
            if (l15 == 0) atomicAdd(rowsum + gi, s);
        }
    }
}

// ---------------- Kernel 3: loss = mean(log(rowsum) - diag) ----------------
__global__ __launch_bounds__(1024) void k_final(const float* __restrict__ rowsum,
                                                const float* __restrict__ diag,
                                                float* __restrict__ out) {
    int tid = threadIdx.x;
    float s = 0.f;
#pragma unroll
    for (int i = 0; i < 4; ++i) {
        int idx = tid + 1024 * i;
        s += logf(rowsum[idx]) - diag[idx];
    }
#pragma unroll
    for (int off = 32; off; off >>= 1) s += __shfl_xor(s, off);
    __shared__ float red[16];
    if ((tid & 63) == 0) red[tid >> 6] = s;
    __syncthreads();
    if (tid == 0) {
        float tot = 0.f;
#pragma unroll
        for (int i = 0; i < 16; ++i) tot += red[i];
        out[0] = tot * (1.0f / NROWS);
    }
}

extern "C" void kernel_launch(void* const* d_in, const int* in_sizes, int n_in,
                              void* d_out, int out_size, void* d_ws, size_t ws_size,
                              hipStream_t stream) {
    const float* f1 = (const float*)d_in[0];
    const float* f2 = (const float*)d_in[1];
    float* out = (float*)d_out;

    char* ws = (char*)d_ws;                       // layout: n1 | n2 | rowsum | diag
    unsigned short* n1 = (unsigned short*)ws;
    unsigned short* n2 = n1 + (size_t)NROWS * DIM;
    float* rowsum = (float*)(ws + 2 * (size_t)NROWS * DIM * sizeof(unsigned short));
    float* diag = rowsum + NROWS;

    k_norm<<<2048, 256, 0, stream>>>(f1, f2, n1, n2, rowsum);
    k_gemm_lse<<<256, 512, 0, stream>>>(n1, n2, rowsum, diag);
    k_final<<<1, 1024, 0, stream>>>(rowsum, diag, out);
}